// Round 8
// baseline (554.678 us; speedup 1.0000x reference)
//
#include <hip/hip_runtime.h>

// ReadInAttention — single persistent kernel, 8 phases separated by
// device-scope atomic grid barriers. Grid 448 x 256 (capacity 512 at
// launch_bounds(256,2) -> always co-resident). GEMM core: 4 rows x float4
// per thread, dual 8-deep prefetch buffers, A broadcast from LDS.

#define DD 768
#define CDIM 384
#define NH 8
#define HD 64
#define INNER 512
#define VV 256
#define GRID 448

__device__ __forceinline__ void fma4(float4& a, float s, const float4& b) {
  a.x += s * b.x; a.y += s * b.y; a.z += s * b.z; a.w += s * b.w;
}

template <int K, int NS>
__device__ __forceinline__ void gcore(const float* __restrict__ A0, int lda,
                                      const float* __restrict__ Bp,
                                      float4& a0, float4& a1, float4& a2,
                                      float4& a3) {
  float4 b0[8], b1[8];
#pragma unroll
  for (int i = 0; i < 8; i++) b0[i] = *(const float4*)(Bp + (size_t)i * NS);
  const float* Bq = Bp + (size_t)8 * NS;
#pragma unroll 1
  for (int kk = 0; kk < K; kk += 16) {
#pragma unroll
    for (int i = 0; i < 8; i++) b1[i] = *(const float4*)(Bq + (size_t)i * NS);
    Bq += (size_t)8 * NS;
#pragma unroll
    for (int i = 0; i < 8; i++) {
      float4 bv = b0[i]; int k = kk + i;
      fma4(a0, A0[k], bv); fma4(a1, A0[lda + k], bv);
      fma4(a2, A0[2 * lda + k], bv); fma4(a3, A0[3 * lda + k], bv);
    }
    if (kk + 16 < K) {
#pragma unroll
      for (int i = 0; i < 8; i++) b0[i] = *(const float4*)(Bq + (size_t)i * NS);
      Bq += (size_t)8 * NS;
    }
#pragma unroll
    for (int i = 0; i < 8; i++) {
      float4 bv = b1[i]; int k = kk + 8 + i;
      fma4(a0, A0[k], bv); fma4(a1, A0[lda + k], bv);
      fma4(a2, A0[2 * lda + k], bv); fma4(a3, A0[3 * lda + k], bv);
    }
  }
}

__device__ __forceinline__ void gbar(unsigned* bar, unsigned target) {
  __syncthreads();
  if (threadIdx.x == 0) {
    __threadfence();
    atomicAdd(bar, 1u);
    while (atomicAdd(bar, 0u) < target) __builtin_amdgcn_s_sleep(2);
    __threadfence();
  }
  __syncthreads();
}

__global__ __launch_bounds__(256, 2) void k_all(
    const float* __restrict__ rs, const float* __restrict__ codes,
    const float* __restrict__ ss, const float* __restrict__ g_r,
    const float* __restrict__ b_r, const float* __restrict__ g_s,
    const float* __restrict__ b_s, const float* __restrict__ Wq,
    const float* __restrict__ bq, const float* __restrict__ Wmq,
    const float* __restrict__ Wk, const float* __restrict__ bk,
    const float* __restrict__ Wmk, const float* __restrict__ Wv,
    const float* __restrict__ bvv, const float* __restrict__ Wmv,
    const float* __restrict__ We, const float* __restrict__ be,
    const float* __restrict__ Wme, const float* __restrict__ gamma,
    float* __restrict__ w, float* __restrict__ outp, unsigned* __restrict__ bar) {
  __shared__ float SB[6144];
  float* s_ln = w;                  // 786432   (P1 -> P5)
  float* r_ln = w + 786432;         // 196608   (P1 -> P2)
  float* WkT  = w + 983040;         // 393216   (P1 -> P3)
  float* qp   = w + 1376256;        // 524288   (P2 -> P3, 4 partials)
  float* sT   = w + 1900544;        // 786432   (P2 -> P4)
  float* cp   = w + 2686976;        // 720896   (P1 -> P7) [m][2816]
  float* qbk  = w + 3407872;        // 2048     (P3 -> P5)
  float* qm   = w + 3409920;        // 1572864  (P3 -> P4)
  float* scp  = w + 4982784;        // 2097152  (P4 -> P5, 4 partials)
  float* wsm  = qm;                 // alias (P5 -> P6)
  float* mmp  = r_ln;               // alias r_ln+WkT+qp (P6 -> P7, 8 partials)
  float* op   = scp;                // alias (P7 -> P8, 8 partials)

  int t = threadIdx.x;
  unsigned target = 0;

  // ================= Phase 1: code GEMM | WkT | LN =================
  for (int tile = blockIdx.x; tile < 1552; tile += GRID) {
    if (tile < 176) {
      int nc = tile % 11, mb = tile / 11;
      int base = nc * 256;
      const float* W; int N, colW;
      if (base < 768)       { W = Wmq; N = DD;    colW = base; }
      else if (base < 1536) { W = Wmk; N = DD;    colW = base - 768; }
      else if (base < 2304) { W = Wmv; N = DD;    colW = base - 1536; }
      else                  { W = Wme; N = INNER; colW = base - 2304; }
      int m0 = mb * 16;
#pragma unroll
      for (int p = 0; p < 24; p++) {
        int idx = p * 256 + t, r = idx / 384, k = idx % 384;
        SB[idx] = codes[(size_t)(m0 + r) * CDIM + k];
      }
      __syncthreads();
      int kl = t & 63, wid = t >> 6;
      const float* A0 = SB + (wid * 4) * 384;
      float4 a0 = {0,0,0,0}, a1 = {0,0,0,0}, a2 = {0,0,0,0}, a3 = {0,0,0,0};
      if (N == DD)
        gcore<384, DD>(A0, 384, W + colW + 4 * kl, a0, a1, a2, a3);
      else
        gcore<384, INNER>(A0, 384, W + colW + 4 * kl, a0, a1, a2, a3);
      int m = m0 + wid * 4, gcol = base + 4 * kl;
      *(float4*)(cp + (size_t)m * 2816 + gcol) = a0;
      *(float4*)(cp + (size_t)(m + 1) * 2816 + gcol) = a1;
      *(float4*)(cp + (size_t)(m + 2) * 2816 + gcol) = a2;
      *(float4*)(cp + (size_t)(m + 3) * 2816 + gcol) = a3;
    } else if (tile < 272) {
      int tid = tile - 176;
      int d0 = (tid >> 3) * 64, c0 = (tid & 7) * 64;
      int j = t & 63, i0 = t >> 6;
#pragma unroll
      for (int p = 0; p < 16; p++) {
        int i = p * 4 + i0;
        SB[i * 65 + j] = Wk[(size_t)(d0 + i) * INNER + c0 + j];
      }
      __syncthreads();
#pragma unroll
      for (int p = 0; p < 16; p++) {
        int i = p * 4 + i0;
        WkT[(size_t)(c0 + i) * DD + d0 + j] = SB[j * 65 + i];
      }
    } else {
      int rr = tile - 272;
      const float *x, *g, *bb; float* y; int r;
      if (rr < 1024) { x = ss; g = g_s; bb = b_s; y = s_ln; r = rr; }
      else           { x = rs; g = g_r; bb = b_r; y = r_ln; r = rr - 1024; }
      const float* xr = x + (size_t)r * DD;
      float v0 = xr[t], v1 = xr[t + 256], v2 = xr[t + 512];
      float s = v0 + v1 + v2, sq = v0 * v0 + v1 * v1 + v2 * v2;
      for (int o = 32; o > 0; o >>= 1) {
        s += __shfl_down(s, o, 64); sq += __shfl_down(sq, o, 64);
      }
      int wid = t >> 6, lane = t & 63;
      if (lane == 0) { SB[wid] = s; SB[wid + 4] = sq; }
      __syncthreads();
      float sum = SB[0] + SB[1] + SB[2] + SB[3];
      float ssq = SB[4] + SB[5] + SB[6] + SB[7];
      float mu = sum * (1.0f / 768.0f);
      float var = ssq * (1.0f / 768.0f) - mu * mu;
      float rstd = rsqrtf(var + 1e-5f);
      float* yr = y + (size_t)r * DD;
      yr[t]       = (v0 - mu) * rstd * g[t]       + bb[t];
      yr[t + 256] = (v1 - mu) * rstd * g[t + 256] + bb[t + 256];
      yr[t + 512] = (v2 - mu) * rstd * g[t + 512] + bb[t + 512];
    }
    __syncthreads();
  }
  target += GRID; gbar(bar, target);

  // ================= Phase 2: q partial (128) | sT (192) =================
  for (int tile = blockIdx.x; tile < 320; tile += GRID) {
    if (tile < 128) {
      int ks = tile & 3, t2 = tile >> 2, nc = t2 & 1, mb = t2 >> 1;
      int m0 = mb * 16, col0 = nc * 256, k0 = ks * 192;
#pragma unroll
      for (int p = 0; p < 12; p++) {
        int idx = p * 256 + t, r = idx / 192, k = idx % 192;
        int d = k0 + k;
        float mqv = cp[(size_t)(m0 + r) * 2816 + d] + 1.0f;
        SB[idx] = r_ln[(size_t)(m0 + r) * DD + d] * mqv;
      }
      __syncthreads();
      int kl = t & 63, wid = t >> 6;
      int col = col0 + 4 * kl;
      const float* A0 = SB + (wid * 4) * 192;
      float4 a0 = {0,0,0,0}, a1 = {0,0,0,0}, a2 = {0,0,0,0}, a3 = {0,0,0,0};
      gcore<192, INNER>(A0, 192, Wq + (size_t)k0 * INNER + col, a0, a1, a2, a3);
      int m = m0 + wid * 4;
      float* dst = qp + (size_t)ks * (256 * INNER);
      *(float4*)(dst + (size_t)m * INNER + col) = a0;
      *(float4*)(dst + (size_t)(m + 1) * INNER + col) = a1;
      *(float4*)(dst + (size_t)(m + 2) * INNER + col) = a2;
      *(float4*)(dst + (size_t)(m + 3) * INNER + col) = a3;
    } else {
      int tid = tile - 128;
      int vt = tid & 3, dt = (tid >> 2) % 12, b = tid / 48;
      int v0 = vt * 64, d0 = dt * 64;
      int j = t & 63, i0 = t >> 6;
#pragma unroll
      for (int p = 0; p < 16; p++) {
        int i = p * 4 + i0;
        SB[i * 65 + j] = s_ln[(size_t)(b * VV + v0 + i) * DD + d0 + j];
      }
      __syncthreads();
#pragma unroll
      for (int p = 0; p < 16; p++) {
        int i = p * 4 + i0;
        sT[((size_t)b * DD + d0 + i) * VV + v0 + j] = SB[j * 65 + i];
      }
    }
    __syncthreads();
  }
  target += GRID; gbar(bar, target);

  // ================= Phase 3: qmk (384) | qbk (256) =================
  for (int tile = blockIdx.x; tile < 640; tile += GRID) {
    if (tile < 384) {
      int h = tile & 7, dc = (tile >> 3) % 3, mb = tile / 24;
      int m0 = mb * 16;
#pragma unroll
      for (int p = 0; p < 4; p++) {
        int idx = p * 256 + t, r = idx >> 6, c = idx & 63;
        int i = h * HD + c;
        size_t off = (size_t)(m0 + r) * INNER + i;
        SB[idx] = qp[off] + qp[131072 + off] + qp[262144 + off] +
                  qp[393216 + off] + bq[i];
      }
      __syncthreads();
      int kl = t & 63, wid = t >> 6;
      int col = dc * 256 + 4 * kl;
      const float* A0 = SB + (wid * 4) * HD;
      float4 a0 = {0,0,0,0}, a1 = {0,0,0,0}, a2 = {0,0,0,0}, a3 = {0,0,0,0};
      gcore<64, DD>(A0, HD, WkT + (size_t)(h * HD) * DD + col, a0, a1, a2, a3);
#pragma unroll
      for (int j = 0; j < 4; j++) {
        float4 a = (j == 0) ? a0 : (j == 1) ? a1 : (j == 2) ? a2 : a3;
        int m = m0 + wid * 4 + j;
        const float* mkp = cp + (size_t)m * 2816 + 768 + col;
        float4 o = {a.x * (mkp[0] + 1.0f), a.y * (mkp[1] + 1.0f),
                    a.z * (mkp[2] + 1.0f), a.w * (mkp[3] + 1.0f)};
        *(float4*)(qm + ((size_t)m * NH + h) * DD + col) = o;
      }
    } else {
      int m = tile - 384;
      size_t off = (size_t)m * INNER;
      SB[t] = (qp[off + t] + qp[131072 + off + t] + qp[262144 + off + t] +
               qp[393216 + off + t] + bq[t]) * bk[t];
      int t2 = t + 256;
      SB[t2] = (qp[off + t2] + qp[131072 + off + t2] + qp[262144 + off + t2] +
                qp[393216 + off + t2] + bq[t2]) * bk[t2];
      __syncthreads();
      if (t < 8) {
        float a = 0.f;
        for (int c = 0; c < HD; c++) a += SB[t * HD + c];
        qbk[m * NH + t] = a;
      }
    }
    __syncthreads();
  }
  target += GRID; gbar(bar, target);

  // ================= Phase 4: scores partial (512) =================
  for (int tile = blockIdx.x; tile < 512; tile += GRID) {
    int ks = tile & 3, b = (tile >> 2) & 3, mb = tile >> 4;
    int gi0 = b * 512 + mb * 16, k0 = ks * 192;
#pragma unroll
    for (int p = 0; p < 12; p++) {
      int idx = p * 256 + t, r = idx / 192, k = idx % 192;
      SB[idx] = qm[(size_t)(gi0 + r) * DD + k0 + k];
    }
    __syncthreads();
    int kl = t & 63, wid = t >> 6;
    int col = 4 * kl;
    const float* A0 = SB + (wid * 4) * 192;
    float4 a0 = {0,0,0,0}, a1 = {0,0,0,0}, a2 = {0,0,0,0}, a3 = {0,0,0,0};
    gcore<192, VV>(A0, 192, sT + ((size_t)b * DD + k0) * VV + col, a0, a1, a2, a3);
    int gi = gi0 + wid * 4;
    float* dst = scp + (size_t)ks * (2048 * VV);
    *(float4*)(dst + (size_t)gi * VV + col) = a0;
    *(float4*)(dst + (size_t)(gi + 1) * VV + col) = a1;
    *(float4*)(dst + (size_t)(gi + 2) * VV + col) = a2;
    *(float4*)(dst + (size_t)(gi + 3) * VV + col) = a3;
    __syncthreads();
  }
  target += GRID; gbar(bar, target);

  // ================= Phase 5: softmax + ws GEMM (384) =================
  for (int tile = blockIdx.x; tile < 384; tile += GRID) {
    int dc = tile % 3, up = (tile / 3) % 32, b = tile / 96;
    int gi0 = b * 512 + up * 16;
#pragma unroll
    for (int p = 0; p < 16; p++) {
      int idx = p * 256 + t, r = idx >> 8, c = idx & 255;
      size_t o = (size_t)(gi0 + r) * VV + c;
      float v = scp[o] + scp[524288 + o] + scp[1048576 + o] + scp[1572864 + o];
      int m = b * 64 + up * 2 + (r >> 3), h = r & 7;
      SB[idx] = (v + qbk[m * NH + h]) * 0.125f;
    }
    __syncthreads();
    int wid = t >> 6, lane = t & 63;
#pragma unroll
    for (int j = 0; j < 4; j++) {
      int r = wid * 4 + j;
      float x0 = SB[r * 256 + lane],       x1 = SB[r * 256 + lane + 64];
      float x2 = SB[r * 256 + lane + 128], x3 = SB[r * 256 + lane + 192];
      float mx = fmaxf(fmaxf(x0, x1), fmaxf(x2, x3));
      for (int o = 1; o < 64; o <<= 1) mx = fmaxf(mx, __shfl_xor(mx, o, 64));
      float e0 = __expf(x0 - mx), e1 = __expf(x1 - mx);
      float e2 = __expf(x2 - mx), e3 = __expf(x3 - mx);
      float sm = e0 + e1 + e2 + e3;
      for (int o = 1; o < 64; o <<= 1) sm += __shfl_xor(sm, o, 64);
      float rinv = 1.0f / sm;
      SB[r * 256 + lane] = e0 * rinv;       SB[r * 256 + lane + 64] = e1 * rinv;
      SB[r * 256 + lane + 128] = e2 * rinv; SB[r * 256 + lane + 192] = e3 * rinv;
    }
    __syncthreads();
    int kl = t & 63;
    int col = dc * 256 + 4 * kl;
    const float* A0 = SB + (wid * 4) * 256;
    float4 a0 = {0,0,0,0}, a1 = {0,0,0,0}, a2 = {0,0,0,0}, a3 = {0,0,0,0};
    gcore<VV, DD>(A0, 256, s_ln + (size_t)(b * VV) * DD + col, a0, a1, a2, a3);
#pragma unroll
    for (int j = 0; j < 4; j++) {
      float4 a = (j == 0) ? a0 : (j == 1) ? a1 : (j == 2) ? a2 : a3;
      int r = wid * 4 + j;
      int ul = r >> 3, h = r & 7, m = b * 64 + up * 2 + ul;
      const float* mvp = cp + (size_t)m * 2816 + 1536 + col;
      float4 o = {a.x * (mvp[0] + 1.0f), a.y * (mvp[1] + 1.0f),
                  a.z * (mvp[2] + 1.0f), a.w * (mvp[3] + 1.0f)};
      *(float4*)(wsm + ((size_t)h * 256 + m) * DD + col) = o;
    }
    __syncthreads();
  }
  target += GRID; gbar(bar, target);

  // ================= Phase 6: msg partial (256) =================
  for (int tile = blockIdx.x; tile < 256; tile += GRID) {
    int hp = tile & 1, ks = (tile >> 1) & 7, mb = tile >> 4;
    int h0 = hp * 4, m0 = mb * 16, k0 = ks * 96;
#pragma unroll
    for (int p = 0; p < 24; p++) {
      int idx = p * 256 + t;
      int e = idx / 1536, rem = idx % 1536, r = rem / 96, k = rem % 96;
      SB[idx] = wsm[((size_t)(h0 + e) * 256 + m0 + r) * DD + k0 + k];
    }
    __syncthreads();
    int kl = t & 63, wid = t >> 6;
    int hs = kl >> 4, c4 = 4 * (kl & 15);
    int colg = h0 * HD + hs * HD + c4;
    const float* A0 = SB + (hs * 16 + wid * 4) * 96;
    float4 a0 = {0,0,0,0}, a1 = {0,0,0,0}, a2 = {0,0,0,0}, a3 = {0,0,0,0};
    gcore<96, INNER>(A0, 96, Wv + (size_t)k0 * INNER + colg, a0, a1, a2, a3);
    float* dst = mmp + (size_t)ks * (256 * INNER);
    int m = m0 + wid * 4;
    *(float4*)(dst + (size_t)m * INNER + colg) = a0;
    *(float4*)(dst + (size_t)(m + 1) * INNER + colg) = a1;
    *(float4*)(dst + (size_t)(m + 2) * INNER + colg) = a2;
    *(float4*)(dst + (size_t)(m + 3) * INNER + colg) = a3;
    __syncthreads();
  }
  target += GRID; gbar(bar, target);

  // ================= Phase 7: out partial (384) =================
  for (int tile = blockIdx.x; tile < 384; tile += GRID) {
    int ks = tile & 7, dc = (tile >> 3) % 3, mb = tile / 24;
    int m0 = mb * 16, k0 = ks * 64;
#pragma unroll
    for (int p = 0; p < 4; p++) {
      int idx = p * 256 + t, r = idx >> 6, k = idx & 63;
      int i = k0 + k;
      size_t off = (size_t)(m0 + r) * INNER + i;
      float v = mmp[off] + mmp[131072 + off] + mmp[262144 + off] +
                mmp[393216 + off] + mmp[524288 + off] + mmp[655360 + off] +
                mmp[786432 + off] + mmp[917504 + off];
      float mev = cp[(size_t)(m0 + r) * 2816 + 2304 + i] + 1.0f;
      SB[idx] = (v + bvv[i]) * mev;
    }
    __syncthreads();
    int kl = t & 63, wid = t >> 6;
    int col = dc * 256 + 4 * kl;
    const float* A0 = SB + (wid * 4) * 64;
    float4 a0 = {0,0,0,0}, a1 = {0,0,0,0}, a2 = {0,0,0,0}, a3 = {0,0,0,0};
    gcore<64, DD>(A0, 64, We + (size_t)k0 * DD + col, a0, a1, a2, a3);
    float* dst = op + (size_t)ks * (256 * DD);
    int m = m0 + wid * 4;
    *(float4*)(dst + (size_t)m * DD + col) = a0;
    *(float4*)(dst + (size_t)(m + 1) * DD + col) = a1;
    *(float4*)(dst + (size_t)(m + 2) * DD + col) = a2;
    *(float4*)(dst + (size_t)(m + 3) * DD + col) = a3;
    __syncthreads();
  }
  target += GRID; gbar(bar, target);

  // ================= Phase 8: epilogue (256) =================
  for (int tile = blockIdx.x; tile < 256; tile += GRID) {
    int m = tile;
#pragma unroll
    for (int j = 0; j < 3; j++) {
      int d = t + j * 256;
      size_t off = (size_t)m * DD + d;
      float v = op[off] + op[196608 + off] + op[393216 + off] +
                op[589824 + off] + op[786432 + off] + op[983040 + off] +
                op[1179648 + off] + op[1376256 + off];
      outp[off] = rs[off] + (v + be[d]) * gamma[d];
    }
  }
}

extern "C" void kernel_launch(void* const* d_in, const int* in_sizes, int n_in,
                              void* d_out, int out_size, void* d_ws, size_t ws_size,
                              hipStream_t stream) {
  const float* rs     = (const float*)d_in[0];
  const float* codes  = (const float*)d_in[1];
  const float* ss     = (const float*)d_in[2];
  const float* ln_r_g = (const float*)d_in[3];
  const float* ln_r_b = (const float*)d_in[4];
  const float* ln_s_g = (const float*)d_in[5];
  const float* ln_s_b = (const float*)d_in[6];
  const float* Wq  = (const float*)d_in[7];
  const float* bq  = (const float*)d_in[8];
  const float* Wmq = (const float*)d_in[9];
  const float* Wk  = (const float*)d_in[10];
  const float* bk  = (const float*)d_in[11];
  const float* Wmk = (const float*)d_in[12];
  const float* Wv  = (const float*)d_in[13];
  const float* bv  = (const float*)d_in[14];
  const float* Wmv = (const float*)d_in[15];
  const float* We  = (const float*)d_in[16];
  const float* be  = (const float*)d_in[17];
  const float* Wme = (const float*)d_in[18];
  const float* gamma = (const float*)d_in[19];

  float* w = (float*)d_ws;
  unsigned* bar = (unsigned*)(w + 7079936);   // past 28.3 MB working set

  hipMemsetAsync(bar, 0, 64, stream);
  k_all<<<dim3(GRID), 256, 0, stream>>>(
      rs, codes, ss, ln_r_g, ln_r_b, ln_s_g, ln_s_b, Wq, bq, Wmq, Wk, bk,
      Wmk, Wv, bv, Wmv, We, be, Wme, gamma, w, (float*)d_out, bar);
}